// Round 5
// baseline (6069.905 us; speedup 1.0000x reference)
//
#include <hip/hip_runtime.h>
#include <math.h>

#define VOCAB 8000
#define BATCH 128
#define TMAX  512
#define DIM   256
#define HID   128
#define G4    512     // 4*HID
#define NCOL  1024    // 2*G4 (both directions)

// --- DPP lane ops: VALU-speed (~4cyc). quad_perm ctrl = sel0|sel1<<2|sel2<<4|sel3<<6.
__device__ __forceinline__ float dpp_xor1(float x) {   // [1,0,3,2] = 0xB1
  int r = __builtin_amdgcn_update_dpp(0, __builtin_bit_cast(int, x),
                                      0xB1, 0xF, 0xF, true);
  return __builtin_bit_cast(float, r);
}
__device__ __forceinline__ float dpp_xor2(float x) {   // [2,3,0,1] = 0x4E
  int r = __builtin_amdgcn_update_dpp(0, __builtin_bit_cast(int, x),
                                      0x4E, 0xF, 0xF, true);
  return __builtin_bit_cast(float, r);
}
__device__ __forceinline__ unsigned dpp_xor1u(unsigned x) {
  return (unsigned)__builtin_amdgcn_update_dpp(0, (int)x, 0xB1, 0xF, 0xF, true);
}
__device__ __forceinline__ unsigned dpp_xor2u(unsigned x) {
  return (unsigned)__builtin_amdgcn_update_dpp(0, (int)x, 0x4E, 0xF, 0xF, true);
}
__device__ __forceinline__ float dpp_bc0(float x) {    // broadcast quad lane 0
  int r = __builtin_amdgcn_update_dpp(0, __builtin_bit_cast(int, x),
                                      0x00, 0xF, 0xF, true);
  return __builtin_bit_cast(float, r);
}
__device__ __forceinline__ float dpp_bc1(float x) {
  int r = __builtin_amdgcn_update_dpp(0, __builtin_bit_cast(int, x),
                                      0x55, 0xF, 0xF, true);
  return __builtin_bit_cast(float, r);
}
__device__ __forceinline__ float dpp_bc2(float x) {
  int r = __builtin_amdgcn_update_dpp(0, __builtin_bit_cast(int, x),
                                      0xAA, 0xF, 0xF, true);
  return __builtin_bit_cast(float, r);
}
__device__ __forceinline__ float dpp_bc3(float x) {
  int r = __builtin_amdgcn_update_dpp(0, __builtin_bit_cast(int, x),
                                      0xFF, 0xF, 0xF, true);
  return __builtin_bit_cast(float, r);
}

// LDS-only barrier: per-step exchange is exclusively through LDS.
__device__ __forceinline__ void bar_lds() {
  asm volatile("s_waitcnt lgkmcnt(0)" ::: "memory");
  __builtin_amdgcn_s_barrier();
}

// ---------------------------------------------------------------------------
// Kernel 1: embW[v][n] = emb[v,:] . W_ih_dir[n,:] + b_ih_dir[n] + b_hh_dir[n]
// ---------------------------------------------------------------------------
__global__ __launch_bounds__(256) void embw_gemm(
    const float* __restrict__ emb,
    const float* __restrict__ Wf, const float* __restrict__ Wb,
    const float* __restrict__ bihf, const float* __restrict__ bhhf,
    const float* __restrict__ bihb, const float* __restrict__ bhhb,
    float* __restrict__ embW) {
  __shared__ float As[32][132];   // k-major, padded stride
  __shared__ float Bs[32][132];
  const int tid = threadIdx.x;
  const int m0 = blockIdx.x * 128;
  const int n0 = blockIdx.y * 128;
  const int tx = tid & 15, ty = tid >> 4;
  const int lrow = tid >> 1;            // 0..127
  const int lseg = (tid & 1) * 16;      // 0 or 16 (k offset)
  const float* Wsrc = (n0 < 512) ? Wf : Wb;
  const int nbase = (n0 < 512) ? n0 : (n0 - 512);

  float acc[8][8];
  #pragma unroll
  for (int i = 0; i < 8; ++i)
    #pragma unroll
    for (int jj = 0; jj < 8; ++jj) acc[i][jj] = 0.f;

  for (int k0 = 0; k0 < 256; k0 += 32) {
    const int gm = m0 + lrow;
    #pragma unroll
    for (int q = 0; q < 4; ++q) {
      float4 v = make_float4(0.f, 0.f, 0.f, 0.f);
      if (gm < VOCAB) v = *(const float4*)(emb + (size_t)gm * 256 + k0 + lseg + 4 * q);
      As[lseg + 4*q + 0][lrow] = v.x;
      As[lseg + 4*q + 1][lrow] = v.y;
      As[lseg + 4*q + 2][lrow] = v.z;
      As[lseg + 4*q + 3][lrow] = v.w;
    }
    #pragma unroll
    for (int q = 0; q < 4; ++q) {
      float4 v = *(const float4*)(Wsrc + (size_t)(nbase + lrow) * 256 + k0 + lseg + 4 * q);
      Bs[lseg + 4*q + 0][lrow] = v.x;
      Bs[lseg + 4*q + 1][lrow] = v.y;
      Bs[lseg + 4*q + 2][lrow] = v.z;
      Bs[lseg + 4*q + 3][lrow] = v.w;
    }
    __syncthreads();
    #pragma unroll
    for (int k = 0; k < 32; ++k) {
      float4 av0 = *(const float4*)&As[k][ty * 8];
      float4 av1 = *(const float4*)&As[k][ty * 8 + 4];
      float4 bv0 = *(const float4*)&Bs[k][tx * 4];
      float4 bv1 = *(const float4*)&Bs[k][64 + tx * 4];
      float a[8]  = {av0.x, av0.y, av0.z, av0.w, av1.x, av1.y, av1.z, av1.w};
      float bb[8] = {bv0.x, bv0.y, bv0.z, bv0.w, bv1.x, bv1.y, bv1.z, bv1.w};
      #pragma unroll
      for (int i = 0; i < 8; ++i)
        #pragma unroll
        for (int jj = 0; jj < 8; ++jj)
          acc[i][jj] += a[i] * bb[jj];
    }
    __syncthreads();
  }

  float bias[8];
  #pragma unroll
  for (int jj = 0; jj < 8; ++jj) {
    int n = n0 + ((jj < 4) ? (tx * 4 + jj) : (64 + tx * 4 + (jj - 4)));
    bias[jj] = (n < 512) ? (bihf[n] + bhhf[n]) : (bihb[n - 512] + bhhb[n - 512]);
  }
  #pragma unroll
  for (int i = 0; i < 8; ++i) {
    int gm = m0 + ty * 8 + i;
    if (gm >= VOCAB) continue;
    float4 v0 = make_float4(acc[i][0] + bias[0], acc[i][1] + bias[1],
                            acc[i][2] + bias[2], acc[i][3] + bias[3]);
    float4 v1 = make_float4(acc[i][4] + bias[4], acc[i][5] + bias[5],
                            acc[i][6] + bias[6], acc[i][7] + bias[7]);
    *(float4*)(embW + (size_t)gm * NCOL + n0 + tx * 4) = v0;
    *(float4*)(embW + (size_t)gm * NCOL + n0 + 64 + tx * 4) = v1;
  }
}

// ---------------------------------------------------------------------------
// Kernel 2: masked LSTM recurrence — R5 STRUCTURAL change: 256 threads,
// 1 wave/SIMD (waves_per_eu(1,1)). Theory: R0-R4 showed ~1000 idle cyc/step
// that no instruction-level edit moves; candidates are (a) intra-SIMD wave
// skew (2 waves/SIMD contend for the issue port, finish ~250cyc apart, the
// per-step barrier exposes the skew) and (b) post-barrier LDS read burst
// (64 ds_read_b128 ~ 768cyc pipe > 512cyc FMA issue). With 1 wave/SIMD:
// no contention/skew; burst halves to 32 reads (~384cyc < 512, hidden).
// Each thread now owns 2 units (uA=u2, uB=64+u2): 256 MACs in 32 acc chains;
// per-SIMD FMA issue unchanged (1 wave x 256 inst x 2cyc = 512cyc floor).
// 256 weights live in AGPRs ("+a" pins; a-file = 256/wave, exact fit; legal
// at 1 wave/SIMD where the full unified 512-reg budget is per-wave).
// Tail (reduce/exchange/act) is R1-verbatim, duplicated per unit (pure ILP).
// ---------------------------------------------------------------------------
#define REP8(M) M(0) M(1) M(2) M(3) M(4) M(5) M(6) M(7)
#define REPI8(M,G,U) M(G,U,0) M(G,U,1) M(G,U,2) M(G,U,3) \
                     M(G,U,4) M(G,U,5) M(G,U,6) M(G,U,7)
#define REPALL(M) REPI8(M,0,0) REPI8(M,1,0) REPI8(M,2,0) REPI8(M,3,0) \
                  REPI8(M,0,1) REPI8(M,1,1) REPI8(M,2,1) REPI8(M,3,1)

__global__ __launch_bounds__(256)
__attribute__((amdgpu_waves_per_eu(1, 1)))
void lstm_rec(
    const int* __restrict__ pad_seq, const int* __restrict__ lens,
    const float* __restrict__ Whh_f, const float* __restrict__ Whh_b,
    const float* __restrict__ embW, const float* __restrict__ W_lab,
    float* __restrict__ e_part) {
  const int dir = blockIdx.x & 1;
  const int b   = blockIdx.x >> 1;
  const int tid = threadIdx.x;
  const int q   = tid & 3;       // K-quarter / gate owner 0..3
  const int u2  = tid >> 2;      // 0..63; owns units uA=u2, uB=64+u2
  const int parity = q & 1;
  const int half   = (q >> 1) & 1;

  __shared__ float ring[8][4][36];   // [slot][chunk][32 + 4 pad]
  __shared__ float wls[4][132];      // W_lab cols for MY direction, padded
  __shared__ int   tok[TMAX];

  tok[tid]       = pad_seq[b * TMAX + tid];
  tok[tid + 256] = pad_seq[b * TMAX + tid + 256];
  {
    const int i0 = tid, i1 = tid + 256;
    wls[i0 >> 7][i0 & 127] = W_lab[(i0 >> 7) * DIM + dir * HID + (i0 & 127)];
    wls[i1 >> 7][i1 & 127] = W_lab[(i1 >> 7) * DIM + dir * HID + (i1 & 127)];
  }
  if (tid < 144) ((float*)ring)[tid] = 0.f;    // slot 0 = h(-1) = 0

  const int len = lens[b];
  const float* __restrict__ Whh = dir ? Whh_b : Whh_f;

  // W_hh: 8 rows (4 gates x 2 units) x 32-col K-quarter = 256 pinned scalars
#define DECLP(G,U)                                                      \
  const float4* wr##G##U = (const float4*)(Whh +                        \
      (size_t)((G) * HID + ((U) ? 64 + u2 : u2)) * HID + 32 * q);
  DECLP(0,0) DECLP(1,0) DECLP(2,0) DECLP(3,0)
  DECLP(0,1) DECLP(1,1) DECLP(2,1) DECLP(3,1)
#undef DECLP
#define DECLW(G,U,I)                                                    \
  float w##G##U##_##I##_0, w##G##U##_##I##_1,                           \
        w##G##U##_##I##_2, w##G##U##_##I##_3;                           \
  { float4 t = wr##G##U[I];                                             \
    w##G##U##_##I##_0 = t.x; w##G##U##_##I##_1 = t.y;                   \
    w##G##U##_##I##_2 = t.z; w##G##U##_##I##_3 = t.w; }                 \
  asm volatile("" : "+a"(w##G##U##_##I##_0));                           \
  asm volatile("" : "+a"(w##G##U##_##I##_1));                           \
  asm volatile("" : "+a"(w##G##U##_##I##_2));                           \
  asm volatile("" : "+a"(w##G##U##_##I##_3));
  REPALL(DECLW)
#undef DECLW

#define KEEPW(G,U,I)                                                    \
  asm volatile("" : "+a"(w##G##U##_##I##_0), "+a"(w##G##U##_##I##_1),   \
                    "+a"(w##G##U##_##I##_2), "+a"(w##G##U##_##I##_3));

  float cA = 0.f, cB = 0.f;
  const float ascale = (q == 2) ? 2.f : 1.f;     // tanh(x)=2*sig(2x)-1 for g
  const float* __restrict__ ecolA = embW + dir * G4 + (q * HID + u2);
  const float* __restrict__ ecolB = embW + dir * G4 + (q * HID + 64 + u2);
  float* __restrict__ ep = e_part + (size_t)(dir * BATCH + b) * TMAX * 4;

  bar_lds();

  // batched x@Wih gathers for the next 8 steps, both units (ride across
  // lgkm-only barriers; per-use vmcnt(N) waits)
  float xa0, xa1, xa2, xa3, xa4, xa5, xa6, xa7;
  float xc0, xc1, xc2, xc3, xc4, xc5, xc6, xc7;
#define PRE(r) { const int ss = nbase + r; xa##r = 0.f; xc##r = 0.f;    \
    if (ss < len) {                                                     \
      const int tt = dir ? (len - 1 - ss) : ss;                         \
      const size_t base = (size_t)tok[tt] * NCOL;                       \
      xa##r = ecolA[base]; xc##r = ecolB[base]; } }
  { const int nbase = 0; REP8(PRE) }

#define MACC(G,U,I)                                                     \
    a##G##U##_0 = fmaf(hv##I.x, w##G##U##_##I##_0, a##G##U##_0);        \
    a##G##U##_1 = fmaf(hv##I.y, w##G##U##_##I##_1, a##G##U##_1);        \
    a##G##U##_2 = fmaf(hv##I.z, w##G##U##_##I##_2, a##G##U##_2);        \
    a##G##U##_3 = fmaf(hv##I.w, w##G##U##_##I##_3, a##G##U##_3);
#define DECLACC(G,U)                                                    \
    float a##G##U##_0=0.f, a##G##U##_1=0.f, a##G##U##_2=0.f, a##G##U##_3=0.f;

#define STEP(r, XA, XB)                                                 \
  {                                                                     \
    const float4* h4 = (const float4*)&ring[r][q][0];                   \
    float4 hv0 = h4[0], hv1 = h4[1], hv2 = h4[2], hv3 = h4[3];          \
    float4 hv4 = h4[4], hv5 = h4[5], hv6 = h4[6], hv7 = h4[7];          \
    DECLACC(0,0) DECLACC(1,0) DECLACC(2,0) DECLACC(3,0)                 \
    DECLACC(0,1) DECLACC(1,1) DECLACC(2,1) DECLACC(3,1)                 \
    REPALL(MACC)                                                        \
    /* unit A: transpose-reduce + exchange (R1-verbatim) */             \
    const float pA0 = (a00_0+a00_1)+(a00_2+a00_3);                      \
    const float pA1 = (a10_0+a10_1)+(a10_2+a10_3);                      \
    const float pA2 = (a20_0+a20_1)+(a20_2+a20_3);                      \
    const float pA3 = (a30_0+a30_1)+(a30_2+a30_3);                      \
    const float pB0 = (a01_0+a01_1)+(a01_2+a01_3);                      \
    const float pB1 = (a11_0+a11_1)+(a11_2+a11_3);                      \
    const float pB2 = (a21_0+a21_1)+(a21_2+a21_3);                      \
    const float pB3 = (a31_0+a31_1)+(a31_2+a31_3);                      \
    const float kloA = parity ? pA1 : pA0, sloA = parity ? pA0 : pA1;   \
    const float khiA = parity ? pA3 : pA2, shiA = parity ? pA2 : pA3;   \
    const float aloA = kloA + dpp_xor1(sloA);                           \
    const float ahiA = khiA + dpp_xor1(shiA);                           \
    const float kbA = half ? ahiA : aloA, sbA = half ? aloA : ahiA;     \
    const float totA = kbA + dpp_xor2(sbA);                             \
    const float kloB = parity ? pB1 : pB0, sloB = parity ? pB0 : pB1;   \
    const float khiB = parity ? pB3 : pB2, shiB = parity ? pB2 : pB3;   \
    const float aloB = kloB + dpp_xor1(sloB);                           \
    const float ahiB = khiB + dpp_xor1(shiB);                           \
    const float kbB = half ? ahiB : aloB, sbB = half ? aloB : ahiB;     \
    const float totB = kbB + dpp_xor2(sbB);                             \
    const float aaA = totA + (XA);                                      \
    const float aaB = totB + (XB);                                      \
    const float sgA = 1.f / (1.f + __expf(-ascale * aaA));              \
    const float sgB = 1.f / (1.f + __expf(-ascale * aaB));              \
    const float avA = (q == 2) ? (2.f * sgA - 1.f) : sgA;               \
    const float avB = (q == 2) ? (2.f * sgB - 1.f) : sgB;               \
    const float e1A = dpp_xor1(avA);                                    \
    const float e2A = dpp_xor2(avA);                                    \
    const float e3A = dpp_xor2(e1A);                                    \
    const float evA  = parity ? e1A : avA, odA  = parity ? avA : e1A;   \
    const float ev2A = parity ? e3A : e2A, od2A = parity ? e2A : e3A;   \
    const float igA = half ? ev2A : evA, fgA = half ? od2A : odA;       \
    const float gtA = half ? evA : ev2A, ogA = half ? odA : od2A;       \
    const float e1B = dpp_xor1(avB);                                    \
    const float e2B = dpp_xor2(avB);                                    \
    const float e3B = dpp_xor2(e1B);                                    \
    const float evB  = parity ? e1B : avB, odB  = parity ? avB : e1B;   \
    const float ev2B = parity ? e3B : e2B, od2B = parity ? e2B : e3B;   \
    const float igB = half ? ev2B : evB, fgB = half ? od2B : odB;       \
    const float gtB = half ? evB : ev2B, ogB = half ? odB : od2B;       \
    cA = fgA * cA + igA * gtA;                                          \
    cB = fgB * cB + igB * gtB;                                          \
    const float s2A = 1.f / (1.f + __expf(-2.f * cA));                  \
    const float s2B = 1.f / (1.f + __expf(-2.f * cB));                  \
    const float hhA = ogA * (2.f * s2A - 1.f);                          \
    const float hhB = ogB * (2.f * s2B - 1.f);                          \
    if (q == 0) {                                                       \
      ring[(r + 1) & 7][u2 >> 5][u2 & 31] = hhA;                        \
      ring[(r + 1) & 7][2 + (u2 >> 5)][u2 & 31] = hhB;                  \
    }                                                                   \
    bar_lds();                                                          \
  }

  for (int s0 = 0; s0 < len; s0 += 8) {
    REPALL(KEEPW)
    const int cnt = (len - s0 < 8) ? (len - s0) : 8;   // block-uniform
    STEP(0, xa0, xc0)
    if (cnt > 1) STEP(1, xa1, xc1)
    if (cnt > 2) STEP(2, xa2, xc2)
    if (cnt > 3) STEP(3, xa3, xc3)
    if (cnt > 4) STEP(4, xa4, xc4)
    if (cnt > 5) STEP(5, xa5, xc5)
    if (cnt > 6) STEP(6, xa6, xc6)
    if (cnt > 7) STEP(7, xa7, xc7)
    // prefetch next group's gathers (no drain: they ride across barriers)
    { const int nbase = s0 + 8; REP8(PRE) }
    // emission partials for this group: (r,l,sub) = 8x4x8 = 256 threads
    {
      const int r = tid >> 5, l = (tid >> 3) & 3, sub = tid & 7;
      if (r < cnt) {
        // h[16*sub .. 16*sub+15] from ring chunks
        const float4* hp = (const float4*)
            &ring[(r + 1) & 7][sub >> 1][(sub & 1) * 16];
        const float4 h0 = hp[0], h1 = hp[1], h2 = hp[2], h3 = hp[3];
        const float4* wp = (const float4*)&wls[l][16 * sub];
        const float4 u0 = wp[0], u1 = wp[1], u2v = wp[2], u3 = wp[3];
        float d = h0.x*u0.x + h0.y*u0.y + h0.z*u0.z + h0.w*u0.w
                + h1.x*u1.x + h1.y*u1.y + h1.z*u1.z + h1.w*u1.w
                + h2.x*u2v.x + h2.y*u2v.y + h2.z*u2v.z + h2.w*u2v.w
                + h3.x*u3.x + h3.y*u3.y + h3.z*u3.z + h3.w*u3.w;
        d += dpp_xor1(d); d += dpp_xor2(d);
        d += __shfl_xor(d, 4);
        if (sub == 0) {
          const int ss = s0 + r;
          const int tt = dir ? (len - 1 - ss) : ss;
          ep[tt * 4 + l] = d;
        }
      }
    }
    bar_lds();
  }
#undef STEP
#undef MACC
#undef DECLACC
#undef PRE
#undef KEEPW
}

// ---------------------------------------------------------------------------
// Kernel 3: Viterbi (emissions pre-reduced into e_part by lstm_rec).
// ---------------------------------------------------------------------------
__global__ __launch_bounds__(512) void viterbi_k(
    const int* __restrict__ lens, const float* __restrict__ e_part,
    const float* __restrict__ b_lab, const float* __restrict__ trans,
    const float* __restrict__ from_BOS, const float* __restrict__ to_EOS,
    int* __restrict__ out) {
  const int b = blockIdx.x;
  const int tid = threadIdx.x;
  __shared__ float sc[TMAX][4];
  __shared__ unsigned btm[TMAX];
  __shared__ int labs[TMAX];
  const int len = lens[b];

  if (tid < len) {
    const float4 f  = *(const float4*)(e_part + ((size_t)b * TMAX + tid) * 4);
    const float4 g2 = *(const float4*)(e_part + ((size_t)(BATCH + b) * TMAX + tid) * 4);
    const float4 bl = *(const float4*)b_lab;
    sc[tid][0] = f.x + g2.x + bl.x;
    sc[tid][1] = f.y + g2.y + bl.y;
    sc[tid][2] = f.z + g2.z + bl.z;
    sc[tid][3] = f.w + g2.w + bl.w;
  }
  __syncthreads();

  // --- DP: lanes 0..3 of wave 0, lane l owns cur-label l ---
  if (tid < 4) {
    const int l = tid;
    float trc0 = trans[0 * 4 + l], trc1 = trans[1 * 4 + l];
    float trc2 = trans[2 * 4 + l], trc3 = trans[3 * 4 + l];
    float best = from_BOS[l] + sc[0][l];
    float e_next = sc[1][l];
    for (int ti = 1; ti < len; ++ti) {
      const float e = e_next;
      e_next = sc[(ti + 1 < TMAX) ? ti + 1 : ti][l];
      const float b0 = dpp_bc0(best);
      const float b1 = dpp_bc1(best);
      const float b2 = dpp_bc2(best);
      const float b3 = dpp_bc3(best);
      // reference add order: (best[p] + e[cur]) + trans[p][cur]; first-max
      float m = (b0 + e) + trc0; int arg = 0;
      float v;
      v = (b1 + e) + trc1; if (v > m) { m = v; arg = 1; }
      v = (b2 + e) + trc2; if (v > m) { m = v; arg = 2; }
      v = (b3 + e) + trc3; if (v > m) { m = v; arg = 3; }
      best = m;
      unsigned av = ((unsigned)arg) << (8 * l);
      av |= dpp_xor1u(av);
      av |= dpp_xor2u(av);
      if (l == 0) btm[ti] = av;
    }
    const float f0 = dpp_bc0(best) + to_EOS[0];
    const float f1 = dpp_bc1(best) + to_EOS[1];
    const float f2 = dpp_bc2(best) + to_EOS[2];
    const float f3 = dpp_bc3(best) + to_EOS[3];
    if (l == 0) {
      float m = f0; int last = 0;
      if (f1 > m) { m = f1; last = 1; }
      if (f2 > m) { m = f2; last = 2; }
      if (f3 > m) { m = f3; last = 3; }
      labs[len - 1] = last;
      int cur = last;
      #pragma unroll 4
      for (int ti = len - 2; ti >= 0; --ti) {
        cur = (int)((btm[ti + 1] >> (8 * cur)) & 255u);
        labs[ti] = cur;
      }
    }
  }
  __syncthreads();
  out[b * TMAX + tid] = (tid < len) ? labs[tid] : 0;
}

// ---------------------------------------------------------------------------
extern "C" void kernel_launch(void* const* d_in, const int* in_sizes, int n_in,
                              void* d_out, int out_size, void* d_ws, size_t ws_size,
                              hipStream_t stream) {
  const int*   pad_seq  = (const int*)d_in[0];
  const int*   lens     = (const int*)d_in[1];
  const float* emb      = (const float*)d_in[2];
  const float* W_ih_f   = (const float*)d_in[3];
  const float* W_hh_f   = (const float*)d_in[4];
  const float* b_ih_f   = (const float*)d_in[5];
  const float* b_hh_f   = (const float*)d_in[6];
  const float* W_ih_b   = (const float*)d_in[7];
  const float* W_hh_b   = (const float*)d_in[8];
  const float* b_ih_b   = (const float*)d_in[9];
  const float* b_hh_b   = (const float*)d_in[10];
  const float* W_lab    = (const float*)d_in[11];
  const float* b_lab    = (const float*)d_in[12];
  const float* trans    = (const float*)d_in[13];
  const float* from_BOS = (const float*)d_in[14];
  const float* to_EOS   = (const float*)d_in[15];
  int* out = (int*)d_out;

  float* embW   = (float*)d_ws;                      // [8000][1024] = 32.8 MB
  float* e_part = embW + (size_t)VOCAB * NCOL;       // [2][B][T][4] = 2 MB

  embw_gemm<<<dim3(63, 8), 256, 0, stream>>>(emb, W_ih_f, W_ih_b,
                                             b_ih_f, b_hh_f, b_ih_b, b_hh_b, embW);
  lstm_rec<<<dim3(2 * BATCH), 256, 0, stream>>>(pad_seq, lens, W_hh_f, W_hh_b,
                                                embW, W_lab, e_part);
  viterbi_k<<<dim3(BATCH), 512, 0, stream>>>(lens, e_part, b_lab, trans,
                                             from_BOS, to_EOS, out);
}

// Round 6
// 722.187 us; speedup vs baseline: 8.4049x; 8.4049x over previous
//
#include <hip/hip_runtime.h>
#include <math.h>

#define VOCAB 8000
#define BATCH 128
#define TMAX  512
#define DIM   256
#define HID   128
#define G4    512     // 4*HID
#define NCOL  1024    // 2*G4 (both directions)

// --- DPP lane ops: VALU-speed (~4cyc). quad_perm ctrl = sel0|sel1<<2|sel2<<4|sel3<<6.
__device__ __forceinline__ float dpp_xor1(float x) {   // [1,0,3,2] = 0xB1
  int r = __builtin_amdgcn_update_dpp(0, __builtin_bit_cast(int, x),
                                      0xB1, 0xF, 0xF, true);
  return __builtin_bit_cast(float, r);
}
__device__ __forceinline__ float dpp_xor2(float x) {   // [2,3,0,1] = 0x4E
  int r = __builtin_amdgcn_update_dpp(0, __builtin_bit_cast(int, x),
                                      0x4E, 0xF, 0xF, true);
  return __builtin_bit_cast(float, r);
}
// xor4 within a 16-lane row: quad-reverse (xor3) then row_half_mirror (xor7).
// Pure VALU (2 DPP), no LDS pipe (R2 lesson: ds_swizzle on the chain = +100cyc).
__device__ __forceinline__ float dpp_xor4(float x) {
  int t = __builtin_amdgcn_update_dpp(0, __builtin_bit_cast(int, x),
                                      0x1B, 0xF, 0xF, true);   // quad_perm [3,2,1,0]
  int r = __builtin_amdgcn_update_dpp(0, t, 0x141, 0xF, 0xF, true); // row_half_mirror
  return __builtin_bit_cast(float, r);
}
__device__ __forceinline__ unsigned dpp_xor1u(unsigned x) {
  return (unsigned)__builtin_amdgcn_update_dpp(0, (int)x, 0xB1, 0xF, 0xF, true);
}
__device__ __forceinline__ unsigned dpp_xor2u(unsigned x) {
  return (unsigned)__builtin_amdgcn_update_dpp(0, (int)x, 0x4E, 0xF, 0xF, true);
}
__device__ __forceinline__ float dpp_bc0(float x) {    // broadcast quad lane 0
  int r = __builtin_amdgcn_update_dpp(0, __builtin_bit_cast(int, x),
                                      0x00, 0xF, 0xF, true);
  return __builtin_bit_cast(float, r);
}
__device__ __forceinline__ float dpp_bc1(float x) {
  int r = __builtin_amdgcn_update_dpp(0, __builtin_bit_cast(int, x),
                                      0x55, 0xF, 0xF, true);
  return __builtin_bit_cast(float, r);
}
__device__ __forceinline__ float dpp_bc2(float x) {
  int r = __builtin_amdgcn_update_dpp(0, __builtin_bit_cast(int, x),
                                      0xAA, 0xF, 0xF, true);
  return __builtin_bit_cast(float, r);
}
__device__ __forceinline__ float dpp_bc3(float x) {
  int r = __builtin_amdgcn_update_dpp(0, __builtin_bit_cast(int, x),
                                      0xFF, 0xF, 0xF, true);
  return __builtin_bit_cast(float, r);
}

// LDS-only barrier: per-step exchange is exclusively through LDS.
__device__ __forceinline__ void bar_lds() {
  asm volatile("s_waitcnt lgkmcnt(0)" ::: "memory");
  __builtin_amdgcn_s_barrier();
}

// ---------------------------------------------------------------------------
// Kernel 1: embW[v][n] = emb[v,:] . W_ih_dir[n,:] + b_ih_dir[n] + b_hh_dir[n]
// ---------------------------------------------------------------------------
__global__ __launch_bounds__(256) void embw_gemm(
    const float* __restrict__ emb,
    const float* __restrict__ Wf, const float* __restrict__ Wb,
    const float* __restrict__ bihf, const float* __restrict__ bhhf,
    const float* __restrict__ bihb, const float* __restrict__ bhhb,
    float* __restrict__ embW) {
  __shared__ float As[32][132];   // k-major, padded stride
  __shared__ float Bs[32][132];
  const int tid = threadIdx.x;
  const int m0 = blockIdx.x * 128;
  const int n0 = blockIdx.y * 128;
  const int tx = tid & 15, ty = tid >> 4;
  const int lrow = tid >> 1;            // 0..127
  const int lseg = (tid & 1) * 16;      // 0 or 16 (k offset)
  const float* Wsrc = (n0 < 512) ? Wf : Wb;
  const int nbase = (n0 < 512) ? n0 : (n0 - 512);

  float acc[8][8];
  #pragma unroll
  for (int i = 0; i < 8; ++i)
    #pragma unroll
    for (int jj = 0; jj < 8; ++jj) acc[i][jj] = 0.f;

  for (int k0 = 0; k0 < 256; k0 += 32) {
    const int gm = m0 + lrow;
    #pragma unroll
    for (int q = 0; q < 4; ++q) {
      float4 v = make_float4(0.f, 0.f, 0.f, 0.f);
      if (gm < VOCAB) v = *(const float4*)(emb + (size_t)gm * 256 + k0 + lseg + 4 * q);
      As[lseg + 4*q + 0][lrow] = v.x;
      As[lseg + 4*q + 1][lrow] = v.y;
      As[lseg + 4*q + 2][lrow] = v.z;
      As[lseg + 4*q + 3][lrow] = v.w;
    }
    #pragma unroll
    for (int q = 0; q < 4; ++q) {
      float4 v = *(const float4*)(Wsrc + (size_t)(nbase + lrow) * 256 + k0 + lseg + 4 * q);
      Bs[lseg + 4*q + 0][lrow] = v.x;
      Bs[lseg + 4*q + 1][lrow] = v.y;
      Bs[lseg + 4*q + 2][lrow] = v.z;
      Bs[lseg + 4*q + 3][lrow] = v.w;
    }
    __syncthreads();
    #pragma unroll
    for (int k = 0; k < 32; ++k) {
      float4 av0 = *(const float4*)&As[k][ty * 8];
      float4 av1 = *(const float4*)&As[k][ty * 8 + 4];
      float4 bv0 = *(const float4*)&Bs[k][tx * 4];
      float4 bv1 = *(const float4*)&Bs[k][64 + tx * 4];
      float a[8]  = {av0.x, av0.y, av0.z, av0.w, av1.x, av1.y, av1.z, av1.w};
      float bb[8] = {bv0.x, bv0.y, bv0.z, bv0.w, bv1.x, bv1.y, bv1.z, bv1.w};
      #pragma unroll
      for (int i = 0; i < 8; ++i)
        #pragma unroll
        for (int jj = 0; jj < 8; ++jj)
          acc[i][jj] += a[i] * bb[jj];
    }
    __syncthreads();
  }

  float bias[8];
  #pragma unroll
  for (int jj = 0; jj < 8; ++jj) {
    int n = n0 + ((jj < 4) ? (tx * 4 + jj) : (64 + tx * 4 + (jj - 4)));
    bias[jj] = (n < 512) ? (bihf[n] + bhhf[n]) : (bihb[n - 512] + bhhb[n - 512]);
  }
  #pragma unroll
  for (int i = 0; i < 8; ++i) {
    int gm = m0 + ty * 8 + i;
    if (gm >= VOCAB) continue;
    float4 v0 = make_float4(acc[i][0] + bias[0], acc[i][1] + bias[1],
                            acc[i][2] + bias[2], acc[i][3] + bias[3]);
    float4 v1 = make_float4(acc[i][4] + bias[4], acc[i][5] + bias[5],
                            acc[i][6] + bias[6], acc[i][7] + bias[7]);
    *(float4*)(embW + (size_t)gm * NCOL + n0 + tx * 4) = v0;
    *(float4*)(embW + (size_t)gm * NCOL + n0 + 64 + tx * 4) = v1;
  }
}

// ---------------------------------------------------------------------------
// Kernel 2: masked LSTM recurrence — R6 STRUCTURAL test of the R5 theory,
// executed safely. 1024 threads (16 waves, 4/SIMD). Thread = (unit j, gate g,
// K-half kh): owns 64 weights (one gate row half). Per-SIMD FMA floor is
// unchanged (16w x 64inst x 2cyc / 4 SIMD = 512cyc); what changes is 4-way
// wave interleave over the dependent tail + turnaround (2-way before), and a
// SHORTER tail (K-reduce = one dpp_xor1; exchange = R1 mask pattern on
// {xor2, xor4}, all pure-VALU DPP; still ONE exp per lane -- R3 lesson).
// Safety (R5 lessons): "+v" pins only, __launch_bounds__(1024,4) forces
// <=128 VGPR so the 16-wave block is always schedulable; h loads consumed
// immediately to keep live ranges short. h-reads are 2-address wave
// broadcasts (free, m136).
// ---------------------------------------------------------------------------
#define REP8(M) M(0) M(1) M(2) M(3) M(4) M(5) M(6) M(7)
#define REP16(M) M(0) M(1) M(2) M(3) M(4) M(5) M(6) M(7) \
                 M(8) M(9) M(10) M(11) M(12) M(13) M(14) M(15)

__global__ __launch_bounds__(1024, 4)
void lstm_rec(
    const int* __restrict__ pad_seq, const int* __restrict__ lens,
    const float* __restrict__ Whh_f, const float* __restrict__ Whh_b,
    const float* __restrict__ embW, const float* __restrict__ W_lab,
    float* __restrict__ e_part) {
  const int dir = blockIdx.x & 1;
  const int b   = blockIdx.x >> 1;
  const int tid = threadIdx.x;
  const int j   = tid >> 3;        // hidden unit 0..127
  const int s   = tid & 7;         // sub-slot
  const int g   = s >> 1;          // gate 0..3
  const int kh  = s & 1;           // K-half 0..1
  const int parity = g & 1;
  const int half   = g >> 1;

  __shared__ float ring[8][4][36];   // [slot][chunk][32 + 4 pad]
  __shared__ float wls[4][132];      // W_lab cols for MY direction, padded
  __shared__ int   tok[TMAX];

  if (tid < TMAX) tok[tid] = pad_seq[b * TMAX + tid];
  if (tid < 512)
    wls[tid >> 7][tid & 127] = W_lab[(tid >> 7) * DIM + dir * HID + (tid & 127)];
  if (tid < 144) ((float*)ring)[tid] = 0.f;    // slot 0 = h(-1) = 0

  const int len = lens[b];
  const float* __restrict__ Whh = dir ? Whh_b : Whh_f;

  // W_hh: my gate row's K-half = 64 floats = 16 float4, pinned "+v".
  const float4* wr = (const float4*)(Whh + (size_t)(g * HID + j) * HID + kh * 64);
#define DECLW(I)                                                        \
  float w##I##_0, w##I##_1, w##I##_2, w##I##_3;                         \
  { float4 t = wr[I];                                                   \
    w##I##_0 = t.x; w##I##_1 = t.y; w##I##_2 = t.z; w##I##_3 = t.w; }   \
  asm volatile("" : "+v"(w##I##_0));                                    \
  asm volatile("" : "+v"(w##I##_1));                                    \
  asm volatile("" : "+v"(w##I##_2));                                    \
  asm volatile("" : "+v"(w##I##_3));
  REP16(DECLW)
#undef DECLW

#define KEEPW(I)                                                        \
  asm volatile("" : "+v"(w##I##_0), "+v"(w##I##_1),                     \
                    "+v"(w##I##_2), "+v"(w##I##_3));

  float c = 0.f;
  const float ascale = (g == 2) ? 2.f : 1.f;     // tanh(x)=2*sig(2x)-1 for g-gate
  const float* __restrict__ ecol = embW + dir * G4 + (g * HID + j);
  float* __restrict__ ep = e_part + (size_t)(dir * BATCH + b) * TMAX * 4;

  bar_lds();

  // batched x@Wih gathers for the next 8 steps (ride across lgkm-only
  // barriers; per-use vmcnt(N) waits). kh-duplicated, harmless.
  float xb0, xb1, xb2, xb3, xb4, xb5, xb6, xb7;
#define PRE(r) { const int ss = nbase + r; xb##r = 0.f;                 \
    if (ss < len) {                                                     \
      const int tt = dir ? (len - 1 - ss) : ss;                         \
      xb##r = ecol[(size_t)tok[tt] * NCOL]; } }
  { const int nbase = 0; REP8(PRE) }

  // h for my K-half: chunks 2kh, 2kh+1 (32 floats each). Load-and-consume.
#define MACCA(I)                                                        \
  { float4 hv = hA[I];                                                  \
    a0 = fmaf(hv.x, w##I##_0, a0); a1 = fmaf(hv.y, w##I##_1, a1);       \
    a2 = fmaf(hv.z, w##I##_2, a2); a3 = fmaf(hv.w, w##I##_3, a3); }
#define MACCB(I, I8)                                                    \
  { float4 hv = hB[I];                                                  \
    a0 = fmaf(hv.x, w##I8##_0, a0); a1 = fmaf(hv.y, w##I8##_1, a1);     \
    a2 = fmaf(hv.z, w##I8##_2, a2); a3 = fmaf(hv.w, w##I8##_3, a3); }

#define STEP(r, XW)                                                     \
  {                                                                     \
    const float4* hA = (const float4*)&ring[r][2 * kh][0];              \
    const float4* hB = (const float4*)&ring[r][2 * kh + 1][0];          \
    float a0 = 0.f, a1 = 0.f, a2 = 0.f, a3 = 0.f;                       \
    MACCA(0) MACCA(1) MACCA(2) MACCA(3)                                 \
    MACCA(4) MACCA(5) MACCA(6) MACCA(7)                                 \
    MACCB(0, 8)  MACCB(1, 9)  MACCB(2, 10) MACCB(3, 11)                 \
    MACCB(4, 12) MACCB(5, 13) MACCB(6, 14) MACCB(7, 15)                 \
    const float p = (a0 + a1) + (a2 + a3);                              \
    /* K-half reduce: one DPP (kh pairs are lane-adjacent) */           \
    const float tot = p + dpp_xor1(p);                                  \
    const float aa = tot + (XW);                                        \
    const float sg = 1.f / (1.f + __expf(-ascale * aa));                \
    const float act = (g == 2) ? (2.f * sg - 1.f) : sg;                 \
    /* gate exchange across 8-lane group: R1 mask pattern on xor2/xor4 */ \
    const float e1 = dpp_xor2(act);                                     \
    const float e2 = dpp_xor4(act);                                     \
    const float e3 = dpp_xor4(e1);                                      \
    const float ev  = parity ? e1 : act, od  = parity ? act : e1;       \
    const float ev2 = parity ? e3 : e2,  od2 = parity ? e2 : e3;        \
    const float ig = half ? ev2 : ev, fg = half ? od2 : od;             \
    const float gt = half ? ev : ev2, og = half ? od : od2;             \
    c = fg * c + ig * gt;                                               \
    const float s2 = 1.f / (1.f + __expf(-2.f * c));                    \
    const float hh = og * (2.f * s2 - 1.f);                             \
    if (s == 0) ring[(r + 1) & 7][j >> 5][j & 31] = hh;                 \
    bar_lds();                                                          \
  }

  for (int s0 = 0; s0 < len; s0 += 8) {
    REP16(KEEPW)
    const int cnt = (len - s0 < 8) ? (len - s0) : 8;   // block-uniform
    STEP(0, xb0)
    if (cnt > 1) STEP(1, xb1)
    if (cnt > 2) STEP(2, xb2)
    if (cnt > 3) STEP(3, xb3)
    if (cnt > 4) STEP(4, xb4)
    if (cnt > 5) STEP(5, xb5)
    if (cnt > 6) STEP(6, xb6)
    if (cnt > 7) STEP(7, xb7)
    // prefetch next group's gathers (no drain: they ride across barriers)
    { const int nbase = s0 + 8; REP8(PRE) }
    // emission partials (R1-verbatim): (r,l,sub) = 8x4x16; tid>=512 -> r>=8
    // >= cnt -> idle automatically.
    {
      const int r = tid >> 6, l = (tid >> 4) & 3, sub = tid & 15;
      if (r < cnt) {
        const float4* hp = (const float4*)&ring[(r + 1) & 7][sub >> 2][8 * (sub & 3)];
        const float4 h0 = hp[0], h1 = hp[1];
        const float4* wp = (const float4*)&wls[l][8 * sub];
        const float4 u0 = wp[0], u1 = wp[1];
        float d = h0.x*u0.x + h0.y*u0.y + h0.z*u0.z + h0.w*u0.w
                + h1.x*u1.x + h1.y*u1.y + h1.z*u1.z + h1.w*u1.w;
        d += dpp_xor1(d); d += dpp_xor2(d);
        d += __shfl_xor(d, 4); d += __shfl_xor(d, 8);
        if (sub == 0) {
          const int ss = s0 + r;
          const int tt = dir ? (len - 1 - ss) : ss;
          ep[tt * 4 + l] = d;
        }
      }
    }
    bar_lds();
  }
#undef STEP
#undef MACCA
#undef MACCB
#undef PRE
#undef KEEPW
}

// ---------------------------------------------------------------------------
// Kernel 3: Viterbi (emissions pre-reduced into e_part by lstm_rec).
// ---------------------------------------------------------------------------
__global__ __launch_bounds__(512) void viterbi_k(
    const int* __restrict__ lens, const float* __restrict__ e_part,
    const float* __restrict__ b_lab, const float* __restrict__ trans,
    const float* __restrict__ from_BOS, const float* __restrict__ to_EOS,
    int* __restrict__ out) {
  const int b = blockIdx.x;
  const int tid = threadIdx.x;
  __shared__ float sc[TMAX][4];
  __shared__ unsigned btm[TMAX];
  __shared__ int labs[TMAX];
  const int len = lens[b];

  if (tid < len) {
    const float4 f  = *(const float4*)(e_part + ((size_t)b * TMAX + tid) * 4);
    const float4 g2 = *(const float4*)(e_part + ((size_t)(BATCH + b) * TMAX + tid) * 4);
    const float4 bl = *(const float4*)b_lab;
    sc[tid][0] = f.x + g2.x + bl.x;
    sc[tid][1] = f.y + g2.y + bl.y;
    sc[tid][2] = f.z + g2.z + bl.z;
    sc[tid][3] = f.w + g2.w + bl.w;
  }
  __syncthreads();

  // --- DP: lanes 0..3 of wave 0, lane l owns cur-label l ---
  if (tid < 4) {
    const int l = tid;
    float trc0 = trans[0 * 4 + l], trc1 = trans[1 * 4 + l];
    float trc2 = trans[2 * 4 + l], trc3 = trans[3 * 4 + l];
    float best = from_BOS[l] + sc[0][l];
    float e_next = sc[1][l];
    for (int ti = 1; ti < len; ++ti) {
      const float e = e_next;
      e_next = sc[(ti + 1 < TMAX) ? ti + 1 : ti][l];
      const float b0 = dpp_bc0(best);
      const float b1 = dpp_bc1(best);
      const float b2 = dpp_bc2(best);
      const float b3 = dpp_bc3(best);
      // reference add order: (best[p] + e[cur]) + trans[p][cur]; first-max
      float m = (b0 + e) + trc0; int arg = 0;
      float v;
      v = (b1 + e) + trc1; if (v > m) { m = v; arg = 1; }
      v = (b2 + e) + trc2; if (v > m) { m = v; arg = 2; }
      v = (b3 + e) + trc3; if (v > m) { m = v; arg = 3; }
      best = m;
      unsigned av = ((unsigned)arg) << (8 * l);
      av |= dpp_xor1u(av);
      av |= dpp_xor2u(av);
      if (l == 0) btm[ti] = av;
    }
    const float f0 = dpp_bc0(best) + to_EOS[0];
    const float f1 = dpp_bc1(best) + to_EOS[1];
    const float f2 = dpp_bc2(best) + to_EOS[2];
    const float f3 = dpp_bc3(best) + to_EOS[3];
    if (l == 0) {
      float m = f0; int last = 0;
      if (f1 > m) { m = f1; last = 1; }
      if (f2 > m) { m = f2; last = 2; }
      if (f3 > m) { m = f3; last = 3; }
      labs[len - 1] = last;
      int cur = last;
      #pragma unroll 4
      for (int ti = len - 2; ti >= 0; --ti) {
        cur = (int)((btm[ti + 1] >> (8 * cur)) & 255u);
        labs[ti] = cur;
      }
    }
  }
  __syncthreads();
  out[b * TMAX + tid] = (tid < len) ? labs[tid] : 0;
}

// ---------------------------------------------------------------------------
extern "C" void kernel_launch(void* const* d_in, const int* in_sizes, int n_in,
                              void* d_out, int out_size, void* d_ws, size_t ws_size,
                              hipStream_t stream) {
  const int*   pad_seq  = (const int*)d_in[0];
  const int*   lens     = (const int*)d_in[1];
  const float* emb      = (const float*)d_in[2];
  const float* W_ih_f   = (const float*)d_in[3];
  const float* W_hh_f   = (const float*)d_in[4];
  const float* b_ih_f   = (const float*)d_in[5];
  const float* b_hh_f   = (const float*)d_in[6];
  const float* W_ih_b   = (const float*)d_in[7];
  const float* W_hh_b   = (const float*)d_in[8];
  const float* b_ih_b   = (const float*)d_in[9];
  const float* b_hh_b   = (const float*)d_in[10];
  const float* W_lab    = (const float*)d_in[11];
  const float* b_lab    = (const float*)d_in[12];
  const float* trans    = (const float*)d_in[13];
  const float* from_BOS = (const float*)d_in[14];
  const float* to_EOS   = (const float*)d_in[15];
  int* out = (int*)d_out;

  float* embW   = (float*)d_ws;                      // [8000][1024] = 32.8 MB
  float* e_part = embW + (size_t)VOCAB * NCOL;       // [2][B][T][4] = 2 MB

  embw_gemm<<<dim3(63, 8), 256, 0, stream>>>(emb, W_ih_f, W_ih_b,
                                             b_ih_f, b_hh_f, b_ih_b, b_hh_b, embW);
  lstm_rec<<<dim3(2 * BATCH), 1024, 0, stream>>>(pad_seq, lens, W_hh_f, W_hh_b,
                                                 embW, W_lab, e_part);
  viterbi_k<<<dim3(BATCH), 512, 0, stream>>>(lens, e_part, b_lab, trans,
                                             from_BOS, to_EOS, out);
}

// Round 7
// 630.089 us; speedup vs baseline: 9.6334x; 1.1462x over previous
//
#include <hip/hip_runtime.h>
#include <math.h>

#define VOCAB 8000
#define BATCH 128
#define TMAX  512
#define DIM   256
#define HID   128
#define G4    512     // 4*HID
#define NCOL  1024    // 2*G4 (both directions)

// --- DPP lane ops: VALU-speed (~4cyc). quad_perm ctrl = sel0|sel1<<2|sel2<<4|sel3<<6.
__device__ __forceinline__ float dpp_xor1(float x) {   // [1,0,3,2] = 0xB1
  int r = __builtin_amdgcn_update_dpp(0, __builtin_bit_cast(int, x),
                                      0xB1, 0xF, 0xF, true);
  return __builtin_bit_cast(float, r);
}
__device__ __forceinline__ float dpp_xor2(float x) {   // [2,3,0,1] = 0x4E
  int r = __builtin_amdgcn_update_dpp(0, __builtin_bit_cast(int, x),
                                      0x4E, 0xF, 0xF, true);
  return __builtin_bit_cast(float, r);
}
// xor4 within a 16-lane row: quad-reverse (xor3) then row_half_mirror (xor7).
// Pure VALU (2 DPP), no LDS pipe (R2 lesson: ds_swizzle on the chain = +100cyc).
__device__ __forceinline__ float dpp_xor4(float x) {
  int t = __builtin_amdgcn_update_dpp(0, __builtin_bit_cast(int, x),
                                      0x1B, 0xF, 0xF, true);   // quad_perm [3,2,1,0]
  int r = __builtin_amdgcn_update_dpp(0, t, 0x141, 0xF, 0xF, true); // row_half_mirror
  return __builtin_bit_cast(float, r);
}
__device__ __forceinline__ unsigned dpp_xor1u(unsigned x) {
  return (unsigned)__builtin_amdgcn_update_dpp(0, (int)x, 0xB1, 0xF, 0xF, true);
}
__device__ __forceinline__ unsigned dpp_xor2u(unsigned x) {
  return (unsigned)__builtin_amdgcn_update_dpp(0, (int)x, 0x4E, 0xF, 0xF, true);
}
__device__ __forceinline__ float dpp_bc0(float x) {    // broadcast quad lane 0
  int r = __builtin_amdgcn_update_dpp(0, __builtin_bit_cast(int, x),
                                      0x00, 0xF, 0xF, true);
  return __builtin_bit_cast(float, r);
}
__device__ __forceinline__ float dpp_bc1(float x) {
  int r = __builtin_amdgcn_update_dpp(0, __builtin_bit_cast(int, x),
                                      0x55, 0xF, 0xF, true);
  return __builtin_bit_cast(float, r);
}
__device__ __forceinline__ float dpp_bc2(float x) {
  int r = __builtin_amdgcn_update_dpp(0, __builtin_bit_cast(int, x),
                                      0xAA, 0xF, 0xF, true);
  return __builtin_bit_cast(float, r);
}
__device__ __forceinline__ float dpp_bc3(float x) {
  int r = __builtin_amdgcn_update_dpp(0, __builtin_bit_cast(int, x),
                                      0xFF, 0xF, 0xF, true);
  return __builtin_bit_cast(float, r);
}

// LDS-only barrier: per-step exchange is exclusively through LDS.
__device__ __forceinline__ void bar_lds() {
  asm volatile("s_waitcnt lgkmcnt(0)" ::: "memory");
  __builtin_amdgcn_s_barrier();
}

// ---------------------------------------------------------------------------
// Kernel 1: embW[v][n] = emb[v,:] . W_ih_dir[n,:] + b_ih_dir[n] + b_hh_dir[n]
// (unchanged -- exact bit-for-bit output preserved; one change per round)
// ---------------------------------------------------------------------------
__global__ __launch_bounds__(256) void embw_gemm(
    const float* __restrict__ emb,
    const float* __restrict__ Wf, const float* __restrict__ Wb,
    const float* __restrict__ bihf, const float* __restrict__ bhhf,
    const float* __restrict__ bihb, const float* __restrict__ bhhb,
    float* __restrict__ embW) {
  __shared__ float As[32][132];   // k-major, padded stride
  __shared__ float Bs[32][132];
  const int tid = threadIdx.x;
  const int m0 = blockIdx.x * 128;
  const int n0 = blockIdx.y * 128;
  const int tx = tid & 15, ty = tid >> 4;
  const int lrow = tid >> 1;            // 0..127
  const int lseg = (tid & 1) * 16;      // 0 or 16 (k offset)
  const float* Wsrc = (n0 < 512) ? Wf : Wb;
  const int nbase = (n0 < 512) ? n0 : (n0 - 512);

  float acc[8][8];
  #pragma unroll
  for (int i = 0; i < 8; ++i)
    #pragma unroll
    for (int jj = 0; jj < 8; ++jj) acc[i][jj] = 0.f;

  for (int k0 = 0; k0 < 256; k0 += 32) {
    const int gm = m0 + lrow;
    #pragma unroll
    for (int q = 0; q < 4; ++q) {
      float4 v = make_float4(0.f, 0.f, 0.f, 0.f);
      if (gm < VOCAB) v = *(const float4*)(emb + (size_t)gm * 256 + k0 + lseg + 4 * q);
      As[lseg + 4*q + 0][lrow] = v.x;
      As[lseg + 4*q + 1][lrow] = v.y;
      As[lseg + 4*q + 2][lrow] = v.z;
      As[lseg + 4*q + 3][lrow] = v.w;
    }
    #pragma unroll
    for (int q = 0; q < 4; ++q) {
      float4 v = *(const float4*)(Wsrc + (size_t)(nbase + lrow) * 256 + k0 + lseg + 4 * q);
      Bs[lseg + 4*q + 0][lrow] = v.x;
      Bs[lseg + 4*q + 1][lrow] = v.y;
      Bs[lseg + 4*q + 2][lrow] = v.z;
      Bs[lseg + 4*q + 3][lrow] = v.w;
    }
    __syncthreads();
    #pragma unroll
    for (int k = 0; k < 32; ++k) {
      float4 av0 = *(const float4*)&As[k][ty * 8];
      float4 av1 = *(const float4*)&As[k][ty * 8 + 4];
      float4 bv0 = *(const float4*)&Bs[k][tx * 4];
      float4 bv1 = *(const float4*)&Bs[k][64 + tx * 4];
      float a[8]  = {av0.x, av0.y, av0.z, av0.w, av1.x, av1.y, av1.z, av1.w};
      float bb[8] = {bv0.x, bv0.y, bv0.z, bv0.w, bv1.x, bv1.y, bv1.z, bv1.w};
      #pragma unroll
      for (int i = 0; i < 8; ++i)
        #pragma unroll
        for (int jj = 0; jj < 8; ++jj)
          acc[i][jj] += a[i] * bb[jj];
    }
    __syncthreads();
  }

  float bias[8];
  #pragma unroll
  for (int jj = 0; jj < 8; ++jj) {
    int n = n0 + ((jj < 4) ? (tx * 4 + jj) : (64 + tx * 4 + (jj - 4)));
    bias[jj] = (n < 512) ? (bihf[n] + bhhf[n]) : (bihb[n - 512] + bhhb[n - 512]);
  }
  #pragma unroll
  for (int i = 0; i < 8; ++i) {
    int gm = m0 + ty * 8 + i;
    if (gm >= VOCAB) continue;
    float4 v0 = make_float4(acc[i][0] + bias[0], acc[i][1] + bias[1],
                            acc[i][2] + bias[2], acc[i][3] + bias[3]);
    float4 v1 = make_float4(acc[i][4] + bias[4], acc[i][5] + bias[5],
                            acc[i][6] + bias[6], acc[i][7] + bias[7]);
    *(float4*)(embW + (size_t)gm * NCOL + n0 + tx * 4) = v0;
    *(float4*)(embW + (size_t)gm * NCOL + n0 + 64 + tx * 4) = v1;
  }
}

// ---------------------------------------------------------------------------
// Kernel 2: masked LSTM recurrence — R7: the clean 4-waves/SIMD experiment.
// R6's regression was fully explained by LDS-inst amplification (256 vs 64
// wave-b128/step, +751cyc @ ~4cyc/inst); the wave-interleave mechanism was
// never tested. R7 decomposition: 1024 thr, thread = (unit j, K-16th kq):
// owns 4 gates x 16 K-floats = 64 weights (16 float4), reads 4 b128/thread
// -> 64 wave-insts/step == R1. FMA floor/SIMD unchanged (16w x 64 x 2 / 4 =
// 512cyc). Reduce = R1's masked xor1+xor2 stages + ONE composed-DPP xor4
// (pure VALU). Gate exchange / c / h = R1 verbatim (each quad holds gates
// 0..3; one exp per lane). Mechanism under test: 4 independent waves/SIMD
// interleave the tail-latency + barrier-skew phases (2-way before).
// ---------------------------------------------------------------------------
#define REP8(M) M(0) M(1) M(2) M(3) M(4) M(5) M(6) M(7)
#define REP16(M) M(0) M(1) M(2) M(3) M(4) M(5) M(6) M(7) \
                 M(8) M(9) M(10) M(11) M(12) M(13) M(14) M(15)

__global__ __launch_bounds__(1024, 4)
void lstm_rec(
    const int* __restrict__ pad_seq, const int* __restrict__ lens,
    const float* __restrict__ Whh_f, const float* __restrict__ Whh_b,
    const float* __restrict__ embW, const float* __restrict__ W_lab,
    float* __restrict__ e_part) {
  const int dir = blockIdx.x & 1;
  const int b   = blockIdx.x >> 1;
  const int tid = threadIdx.x;
  const int j   = tid >> 3;        // hidden unit 0..127
  const int kq  = tid & 7;         // K-sixteenth 0..7 (16 floats each)
  const int g   = kq & 3;          // my gate after reduce (dup across kq>>2)
  const int parity = g & 1;
  const int half   = g >> 1;

  __shared__ float ring[8][4][36];   // [slot][chunk][32 + 4 pad]
  __shared__ float wls[4][132];      // W_lab cols for MY direction, padded
  __shared__ int   tok[TMAX];

  if (tid < TMAX) tok[tid] = pad_seq[b * TMAX + tid];
  if (tid < 512)
    wls[tid >> 7][tid & 127] = W_lab[(tid >> 7) * DIM + dir * HID + (tid & 127)];
  if (tid < 144) ((float*)ring)[tid] = 0.f;    // slot 0 = h(-1) = 0

  const int len = lens[b];
  const float* __restrict__ Whh = dir ? Whh_b : Whh_f;

  // W_hh: 4 gate rows x 16-float K-slice = 64 pinned scalars ("+v" only).
#define DECLW(I)                                                        \
  float w##I##_0, w##I##_1, w##I##_2, w##I##_3;                         \
  { float4 t = ((const float4*)(Whh +                                   \
        (size_t)(((I) >> 2) * HID + j) * HID + 16 * kq))[(I) & 3];      \
    w##I##_0 = t.x; w##I##_1 = t.y; w##I##_2 = t.z; w##I##_3 = t.w; }   \
  asm volatile("" : "+v"(w##I##_0));                                    \
  asm volatile("" : "+v"(w##I##_1));                                    \
  asm volatile("" : "+v"(w##I##_2));                                    \
  asm volatile("" : "+v"(w##I##_3));
  REP16(DECLW)   // I>>2 = gate, I&3 = float4 index within the 16-float slice
#undef DECLW

#define KEEPW(I)                                                        \
  asm volatile("" : "+v"(w##I##_0), "+v"(w##I##_1),                     \
                    "+v"(w##I##_2), "+v"(w##I##_3));

  float c = 0.f;
  const float ascale = (g == 2) ? 2.f : 1.f;     // tanh(x)=2*sig(2x)-1 for g-gate
  const float* __restrict__ ecol = embW + dir * G4 + (g * HID + j);
  float* __restrict__ ep = e_part + (size_t)(dir * BATCH + b) * TMAX * 4;

  bar_lds();

  // batched x@Wih gathers for the next 8 steps (ride across lgkm-only
  // barriers; per-use vmcnt(N) waits). Duplicated across kq>>2 -- L2 absorbs.
  float xb0, xb1, xb2, xb3, xb4, xb5, xb6, xb7;
#define PRE(r) { const int ss = nbase + r; xb##r = 0.f;                 \
    if (ss < len) {                                                     \
      const int tt = dir ? (len - 1 - ss) : ss;                         \
      xb##r = ecol[(size_t)tok[tt] * NCOL]; } }
  { const int nbase = 0; REP8(PRE) }

  // h slice: floats [16kq..16kq+16) = ring[r][kq>>1][(kq&1)*16 ..]
  // (lane bases -> banks {0,16,4,20,8,24,12,28}: conflict-free broadcast x8)
#define MACC(Q, W0, W1, W2, W3)                                         \
  { float4 hv = h4[Q];                                                  \
    a0 = fmaf(hv.x, w##W0##_0, a0); a0 = fmaf(hv.y, w##W0##_1, a0);     \
    a0 = fmaf(hv.z, w##W0##_2, a0); a0 = fmaf(hv.w, w##W0##_3, a0); }

#define STEP(r, XW)                                                     \
  {                                                                     \
    const float4* h4 = (const float4*)&ring[r][kq >> 1][(kq & 1) * 16]; \
    float4 hv0 = h4[0], hv1 = h4[1], hv2 = h4[2], hv3 = h4[3];          \
    float p0 = 0.f, p1 = 0.f, p2 = 0.f, p3 = 0.f;                       \
    p0 = fmaf(hv0.x, w0_0, p0);  p0 = fmaf(hv0.y, w0_1, p0);            \
    p0 = fmaf(hv0.z, w0_2, p0);  p0 = fmaf(hv0.w, w0_3, p0);            \
    p0 = fmaf(hv1.x, w1_0, p0);  p0 = fmaf(hv1.y, w1_1, p0);            \
    p0 = fmaf(hv1.z, w1_2, p0);  p0 = fmaf(hv1.w, w1_3, p0);            \
    p0 = fmaf(hv2.x, w2_0, p0);  p0 = fmaf(hv2.y, w2_1, p0);            \
    p0 = fmaf(hv2.z, w2_2, p0);  p0 = fmaf(hv2.w, w2_3, p0);            \
    p0 = fmaf(hv3.x, w3_0, p0);  p0 = fmaf(hv3.y, w3_1, p0);            \
    p0 = fmaf(hv3.z, w3_2, p0);  p0 = fmaf(hv3.w, w3_3, p0);            \
    p1 = fmaf(hv0.x, w4_0, p1);  p1 = fmaf(hv0.y, w4_1, p1);            \
    p1 = fmaf(hv0.z, w4_2, p1);  p1 = fmaf(hv0.w, w4_3, p1);            \
    p1 = fmaf(hv1.x, w5_0, p1);  p1 = fmaf(hv1.y, w5_1, p1);            \
    p1 = fmaf(hv1.z, w5_2, p1);  p1 = fmaf(hv1.w, w5_3, p1);            \
    p1 = fmaf(hv2.x, w6_0, p1);  p1 = fmaf(hv2.y, w6_1, p1);            \
    p1 = fmaf(hv2.z, w6_2, p1);  p1 = fmaf(hv2.w, w6_3, p1);            \
    p1 = fmaf(hv3.x, w7_0, p1);  p1 = fmaf(hv3.y, w7_1, p1);            \
    p1 = fmaf(hv3.z, w7_2, p1);  p1 = fmaf(hv3.w, w7_3, p1);            \
    p2 = fmaf(hv0.x, w8_0, p2);  p2 = fmaf(hv0.y, w8_1, p2);            \
    p2 = fmaf(hv0.z, w8_2, p2);  p2 = fmaf(hv0.w, w8_3, p2);            \
    p2 = fmaf(hv1.x, w9_0, p2);  p2 = fmaf(hv1.y, w9_1, p2);            \
    p2 = fmaf(hv1.z, w9_2, p2);  p2 = fmaf(hv1.w, w9_3, p2);            \
    p2 = fmaf(hv2.x, w10_0, p2); p2 = fmaf(hv2.y, w10_1, p2);           \
    p2 = fmaf(hv2.z, w10_2, p2); p2 = fmaf(hv2.w, w10_3, p2);           \
    p2 = fmaf(hv3.x, w11_0, p2); p2 = fmaf(hv3.y, w11_1, p2);           \
    p2 = fmaf(hv3.z, w11_2, p2); p2 = fmaf(hv3.w, w11_3, p2);           \
    p3 = fmaf(hv0.x, w12_0, p3); p3 = fmaf(hv0.y, w12_1, p3);           \
    p3 = fmaf(hv0.z, w12_2, p3); p3 = fmaf(hv0.w, w12_3, p3);           \
    p3 = fmaf(hv1.x, w13_0, p3); p3 = fmaf(hv1.y, w13_1, p3);           \
    p3 = fmaf(hv1.z, w13_2, p3); p3 = fmaf(hv1.w, w13_3, p3);           \
    p3 = fmaf(hv2.x, w14_0, p3); p3 = fmaf(hv2.y, w14_1, p3);           \
    p3 = fmaf(hv2.z, w14_2, p3); p3 = fmaf(hv2.w, w14_3, p3);           \
    p3 = fmaf(hv3.x, w15_0, p3); p3 = fmaf(hv3.y, w15_1, p3);           \
    p3 = fmaf(hv3.z, w15_2, p3); p3 = fmaf(hv3.w, w15_3, p3);           \
    /* 8-lane transpose-reduce: R1's masked xor1/xor2 + one pure-DPP xor4 */ \
    const float klo = parity ? p1 : p0, slo = parity ? p0 : p1;         \
    const float khi = parity ? p3 : p2, shi = parity ? p2 : p3;         \
    const float alo = klo + dpp_xor1(slo);                              \
    const float ahi = khi + dpp_xor1(shi);                              \
    const float kb = half ? ahi : alo, sb = half ? alo : ahi;           \
    const float t2 = kb + dpp_xor2(sb);                                 \
    const float tot = t2 + dpp_xor4(t2);                                \
    const float aa = tot + (XW);                                        \
    const float sg = 1.f / (1.f + __expf(-ascale * aa));                \
    const float act = (g == 2) ? (2.f * sg - 1.f) : sg;                 \
    /* quad exchange of ACTIVATED gates (R1 verbatim; each quad has g0..3) */ \
    const float e1 = dpp_xor1(act);                                     \
    const float e2 = dpp_xor2(act);                                     \
    const float e3 = dpp_xor2(e1);                                      \
    const float ev  = parity ? e1 : act, od  = parity ? act : e1;       \
    const float ev2 = parity ? e3 : e2,  od2 = parity ? e2 : e3;        \
    const float ig = half ? ev2 : ev, fg = half ? od2 : od;             \
    const float gt = half ? ev : ev2, og = half ? od : od2;             \
    c = fg * c + ig * gt;                                               \
    const float s2 = 1.f / (1.f + __expf(-2.f * c));                    \
    const float hh = og * (2.f * s2 - 1.f);                             \
    if (kq == 0) ring[(r + 1) & 7][j >> 5][j & 31] = hh;                \
    bar_lds();                                                          \
  }

  for (int s0 = 0; s0 < len; s0 += 8) {
    REP16(KEEPW)
    const int cnt = (len - s0 < 8) ? (len - s0) : 8;   // block-uniform
    STEP(0, xb0)
    if (cnt > 1) STEP(1, xb1)
    if (cnt > 2) STEP(2, xb2)
    if (cnt > 3) STEP(3, xb3)
    if (cnt > 4) STEP(4, xb4)
    if (cnt > 5) STEP(5, xb5)
    if (cnt > 6) STEP(6, xb6)
    if (cnt > 7) STEP(7, xb7)
    // prefetch next group's gathers (no drain: they ride across barriers)
    { const int nbase = s0 + 8; REP8(PRE) }
    // emission partials (R1-verbatim): (r,l,sub) = 8x4x16; tid>=512 -> r>=8
    // >= cnt -> idle automatically.
    {
      const int r = tid >> 6, l = (tid >> 4) & 3, sub = tid & 15;
      if (r < cnt) {
        const float4* hp = (const float4*)&ring[(r + 1) & 7][sub >> 2][8 * (sub & 3)];
        const float4 h0 = hp[0], h1 = hp[1];
        const float4* wp = (const float4*)&wls[l][8 * sub];
        const float4 u0 = wp[0], u1 = wp[1];
        float d = h0.x*u0.x + h0.y*u0.y + h0.z*u0.z + h0.w*u0.w
                + h1.x*u1.x + h1.y*u1.y + h1.z*u1.z + h1.w*u1.w;
        d += dpp_xor1(d); d += dpp_xor2(d);
        d += __shfl_xor(d, 4); d += __shfl_xor(d, 8);
        if (sub == 0) {
          const int ss = s0 + r;
          const int tt = dir ? (len - 1 - ss) : ss;
          ep[tt * 4 + l] = d;
        }
      }
    }
    bar_lds();
  }
#undef STEP
#undef MACC
#undef PRE
#undef KEEPW
}

// ---------------------------------------------------------------------------
// Kernel 3: Viterbi (emissions pre-reduced into e_part by lstm_rec).
// ---------------------------------------------------------------------------
__global__ __launch_bounds__(512) void viterbi_k(
    const int* __restrict__ lens, const float* __restrict__ e_part,
    const float* __restrict__ b_lab, const float* __restrict__ trans,
    const float* __restrict__ from_BOS, const float* __restrict__ to_EOS,
    int* __restrict__ out) {
  const int b = blockIdx.x;
  const int tid = threadIdx.x;
  __shared__ float sc[TMAX][4];
  __shared__ unsigned btm[TMAX];
  __shared__ int labs[TMAX];
  const int len = lens[b];

  if (tid < len) {
    const float4 f  = *(const float4*)(e_part + ((size_t)b * TMAX + tid) * 4);
    const float4 g2 = *(const float4*)(e_part + ((size_t)(BATCH + b) * TMAX + tid) * 4);
    const float4 bl = *(const float4*)b_lab;
    sc[tid][0] = f.x + g2.x + bl.x;
    sc[tid][1] = f.y + g2.y + bl.y;
    sc[tid][2] = f.z + g2.z + bl.z;
    sc[tid][3] = f.w + g2.w + bl.w;
  }
  __syncthreads();

  // --- DP: lanes 0..3 of wave 0, lane l owns cur-label l ---
  if (tid < 4) {
    const int l = tid;
    float trc0 = trans[0 * 4 + l], trc1 = trans[1 * 4 + l];
    float trc2 = trans[2 * 4 + l], trc3 = trans[3 * 4 + l];
    float best = from_BOS[l] + sc[0][l];
    float e_next = sc[1][l];
    for (int ti = 1; ti < len; ++ti) {
      const float e = e_next;
      e_next = sc[(ti + 1 < TMAX) ? ti + 1 : ti][l];
      const float b0 = dpp_bc0(best);
      const float b1 = dpp_bc1(best);
      const float b2 = dpp_bc2(best);
      const float b3 = dpp_bc3(best);
      // reference add order: (best[p] + e[cur]) + trans[p][cur]; first-max
      float m = (b0 + e) + trc0; int arg = 0;
      float v;
      v = (b1 + e) + trc1; if (v > m) { m = v; arg = 1; }
      v = (b2 + e) + trc2; if (v > m) { m = v; arg = 2; }
      v = (b3 + e) + trc3; if (v > m) { m = v; arg = 3; }
      best = m;
      unsigned av = ((unsigned)arg) << (8 * l);
      av |= dpp_xor1u(av);
      av |= dpp_xor2u(av);
      if (l == 0) btm[ti] = av;
    }
    const float f0 = dpp_bc0(best) + to_EOS[0];
    const float f1 = dpp_bc1(best) + to_EOS[1];
    const float f2 = dpp_bc2(best) + to_EOS[2];
    const float f3 = dpp_bc3(best) + to_EOS[3];
    if (l == 0) {
      float m = f0; int last = 0;
      if (f1 > m) { m = f1; last = 1; }
      if (f2 > m) { m = f2; last = 2; }
      if (f3 > m) { m = f3; last = 3; }
      labs[len - 1] = last;
      int cur = last;
      #pragma unroll 4
      for (int ti = len - 2; ti >= 0; --ti) {
        cur = (int)((btm[ti + 1] >> (8 * cur)) & 255u);
        labs[ti] = cur;
      }
    }
  }
  __syncthreads();
  out[b * TMAX + tid] = (tid < len) ? labs[tid] : 0;
}

// ---------------------------------------------------------------------------
extern "C" void kernel_launch(void* const* d_in, const int* in_sizes, int n_in,
                              void* d_out, int out_size, void* d_ws, size_t ws_size,
                              hipStream_t stream) {
  const int*   pad_seq  = (const int*)d_in[0];
  const int*   lens     = (const int*)d_in[1];
  const float* emb      = (const float*)d_in[2];
  const float* W_ih_f   = (const float*)d_in[3];
  const float* W_hh_f   = (const float*)d_in[4];
  const float* b_ih_f   = (const float*)d_in[5];
  const float* b_hh_f   = (const float*)d_in[6];
  const float* W_ih_b   = (const float*)d_in[7];
  const float* W_hh_b   = (const float*)d_in[8];
  const float* b_ih_b   = (const float*)d_in[9];
  const float* b_hh_b   = (const float*)d_in[10];
  const float* W_lab    = (const float*)d_in[11];
  const float* b_lab    = (const float*)d_in[12];
  const float* trans    = (const float*)d_in[13];
  const float* from_BOS = (const float*)d_in[14];
  const float* to_EOS   = (const float*)d_in[15];
  int* out = (int*)d_out;

  float* embW   = (float*)d_ws;                      // [8000][1024] = 32.8 MB
  float* e_part = embW + (size_t)VOCAB * NCOL;       // [2][B][T][4] = 2 MB

  embw_gemm<<<dim3(63, 8), 256, 0, stream>>>(emb, W_ih_f, W_ih_b,
                                             b_ih_f, b_hh_f, b_ih_b, b_hh_b, embW);
  lstm_rec<<<dim3(2 * BATCH), 1024, 0, stream>>>(pad_seq, lens, W_hh_f, W_hh_b,
                                                 embW, W_lab, e_part);
  viterbi_k<<<dim3(BATCH), 512, 0, stream>>>(lens, e_part, b_lab, trans,
                                             from_BOS, to_EOS, out);
}